// Round 4
// baseline (110.705 us; speedup 1.0000x reference)
//
#include <hip/hip_runtime.h>
#include <hip/hip_bf16.h>
#include <math.h>

#define BSZ 4
#define NN 512
#define DD 64
#define NKEEP 256

typedef __attribute__((ext_vector_type(8))) short short8;
typedef __attribute__((ext_vector_type(4))) float f32x4;

__device__ __forceinline__ ushort f2bf_rne(float f) {
  union { float f; unsigned u; } v; v.f = f;
  unsigned r = v.u + 0x7fffu + ((v.u >> 16) & 1u);
  return (ushort)(r >> 16);
}
__device__ __forceinline__ float bf2f(ushort h) {
  union { unsigned u; float f; } v; v.u = ((unsigned)h) << 16;
  return v.f;
}
__device__ __forceinline__ float fast_tanh(float x) {
  float e = __builtin_amdgcn_exp2f(x * 2.8853900817779268f);
  float r = __builtin_amdgcn_rcpf(e + 1.0f);
  return 1.0f - 2.0f * r;
}

// ============ Kernel A: symmetric partial scores ============================
// grid = (b4, it32, jq4, eh2) = 1024 blocks, 256 thr (4 waves).
// Block: i-tile [it*16,+16), j-range [jq*128,+128) (wave w: 32 j), e-half
// [eh*32,+32) in 4 rounds of 8 e.  Full-skip if all j < all i (mirror covers).
// Partial scores (sum over 32 e of aw[e]*tanh(...)) stored to plane sTp[eh]:
// normal [j][i] iff j>=i, mirror [i][j] iff j>i  (disjoint -> deterministic).
__global__ __launch_bounds__(256, 4) void k_score(
    const float* __restrict__ x, const float* __restrict__ apw,
    const float* __restrict__ apb, const float* __restrict__ aw,
    float* __restrict__ sTp) {
  __shared__ ushort Y8h[8 * 16 * 64];  // 16 KB, swizzled
  __shared__ ushort Y8l[8 * 16 * 64];  // 16 KB

  const int t = threadIdx.x;
  const int w = t >> 6, l = t & 63;
  const int bid = blockIdx.x;
  const int eh = bid & 1;
  const int jq = (bid >> 1) & 3;
  const int it = (bid >> 3) & 31;
  const int b = bid >> 8;
  const int i0 = it * 16;
  if (jq * 128 + 128 <= i0) return;  // fully below diagonal -> mirror covers

  const float* xb = x + (size_t)b * NN * DD;
  const int j0 = jq * 128 + w * 32;
  const bool wave_active = (j0 + 32 > i0);

  // ---- Xi slice into registers: thread handles (i-half, d-quad) in Y-build
  const int p_e = t >> 5;              // e sub-index 0..7
  const int q = t & 31;
  const int ih = (q >> 4) * 8;         // i base (0 or 8)
  const int d0 = (q & 15) * 4;         // d quad base
  float xi_r[8][4];
  #pragma unroll
  for (int i2 = 0; i2 < 8; ++i2) {
    float4 v = *reinterpret_cast<const float4*>(xb + (size_t)(i0 + ih + i2) * DD + d0);
    xi_r[i2][0] = v.x; xi_r[i2][1] = v.y; xi_r[i2][2] = v.z; xi_r[i2][3] = v.w;
  }

  // ---- A fragments (Xj) split hi/lo, e-independent ----
  short8 ah[2][2], al[2][2];
  if (wave_active) {
    const int g = l >> 4;
    #pragma unroll
    for (int jt = 0; jt < 2; ++jt) {
      const int j = j0 + jt * 16 + (l & 15);
      #pragma unroll
      for (int ks = 0; ks < 2; ++ks) {
        const float* xr = xb + (size_t)j * DD + ks * 32 + g * 8;
        float4 u0 = *reinterpret_cast<const float4*>(xr);
        float4 u1 = *reinterpret_cast<const float4*>(xr + 4);
        float vv[8] = {u0.x, u0.y, u0.z, u0.w, u1.x, u1.y, u1.z, u1.w};
        short8 hh, ll;
        #pragma unroll
        for (int qq = 0; qq < 8; ++qq) {
          ushort hq = f2bf_rne(vv[qq]);
          hh[qq] = (short)hq;
          ll[qq] = (short)f2bf_rne(vv[qq] - bf2f(hq));
        }
        ah[jt][ks] = hh; al[jt][ks] = ll;
      }
    }
  }

  f32x4 srews[2];
  srews[0] = (f32x4){0.f, 0.f, 0.f, 0.f};
  srews[1] = (f32x4){0.f, 0.f, 0.f, 0.f};

  #pragma unroll 1
  for (int r = 0; r < 4; ++r) {
    // ---- Y8 build: e = eh*32 + r*8 + p_e; thread covers 8 i x 4 d ----
    {
      const int e = eh * 32 + r * 8 + p_e;
      float wt[4];
      #pragma unroll
      for (int k = 0; k < 4; ++k) wt[k] = apw[(d0 + k) * 64 + e];
      #pragma unroll
      for (int i2 = 0; i2 < 8; ++i2) {
        const int i = ih + i2;
        ushort h4[4], l4[4];
        #pragma unroll
        for (int k = 0; k < 4; ++k) {
          const float v = xi_r[i2][k] * wt[k];
          h4[k] = f2bf_rne(v);
          l4[k] = f2bf_rne(v - bf2f(h4[k]));
        }
        uint2 hw, lw;
        hw.x = (uint)h4[0] | ((uint)h4[1] << 16);
        hw.y = (uint)h4[2] | ((uint)h4[3] << 16);
        lw.x = (uint)l4[0] | ((uint)l4[1] << 16);
        lw.y = (uint)l4[2] | ((uint)l4[3] << 16);
        const int byteoff = (p_e * 2048 + (i * 64 + d0) * 2) ^ ((i & 7) << 4);
        *reinterpret_cast<uint2*>(reinterpret_cast<char*>(Y8h) + byteoff) = hw;
        *reinterpret_cast<uint2*>(reinterpret_cast<char*>(Y8l) + byteoff) = lw;
      }
    }
    __syncthreads();  // Y8 published

    if (wave_active) {
      const int il = l & 15, g = l >> 4;
      #pragma unroll
      for (int p = 0; p < 8; ++p) {
        const int e = eh * 32 + r * 8 + p;
        short8 bh[2], bl[2];
        #pragma unroll
        for (int ks = 0; ks < 2; ++ks) {
          const int byteoff =
              (p * 2048 + (il * 64 + ks * 32 + g * 8) * 2) ^ ((il & 7) << 4);
          bh[ks] = *reinterpret_cast<const short8*>(
              reinterpret_cast<const char*>(Y8h) + byteoff);
          bl[ks] = *reinterpret_cast<const short8*>(
              reinterpret_cast<const char*>(Y8l) + byteoff);
        }
        f32x4 acc[2];
        acc[0] = (f32x4){0.f, 0.f, 0.f, 0.f};
        acc[1] = (f32x4){0.f, 0.f, 0.f, 0.f};
        #pragma unroll
        for (int jt = 0; jt < 2; ++jt)
          #pragma unroll
          for (int ks = 0; ks < 2; ++ks) {
            acc[jt] = __builtin_amdgcn_mfma_f32_16x16x32_bf16(ah[jt][ks], bh[ks], acc[jt], 0, 0, 0);
            acc[jt] = __builtin_amdgcn_mfma_f32_16x16x32_bf16(ah[jt][ks], bl[ks], acc[jt], 0, 0, 0);
            acc[jt] = __builtin_amdgcn_mfma_f32_16x16x32_bf16(al[jt][ks], bh[ks], acc[jt], 0, 0, 0);
          }
        const float bias = apb[e], awv = aw[e];
        #pragma unroll
        for (int jt = 0; jt < 2; ++jt)
          #pragma unroll
          for (int rr = 0; rr < 4; ++rr)
            srews[jt][rr] += awv * fast_tanh(acc[jt][rr] + bias);
      }
    }
    __syncthreads();  // Y8 consumed
  }

  // ---- stores: plane = sTp[eh][b], disjoint ownership ----
  if (wave_active) {
    const int il = l & 15, g = l >> 4;
    const int iv = i0 + il;
    float* plane = sTp + ((size_t)(eh * 4 + b)) * NN * NN;
    #pragma unroll
    for (int jt = 0; jt < 2; ++jt)
      #pragma unroll
      for (int rr = 0; rr < 4; ++rr) {
        const int jv = j0 + jt * 16 + g * 4 + rr;
        const float v = srews[jt][rr];
        if (jv >= iv) plane[(size_t)jv * NN + iv] = v;
        if (jv > iv) plane[(size_t)iv * NN + jv] = v;
      }
  }
}

// ====== Kernel B: per (b,i): softmax + agg + h(BN,SELU) + pool score s =======
__global__ __launch_bounds__(256) void k_soft(
    const float* __restrict__ x, const float* __restrict__ sTp,
    const float* __restrict__ pwa, const float* __restrict__ pwab,
    const float* __restrict__ pwoa, const float* __restrict__ pwob,
    const float* __restrict__ gam, const float* __restrict__ bet,
    const float* __restrict__ mu, const float* __restrict__ var,
    const float* __restrict__ poolw, const float* __restrict__ poolb,
    float* __restrict__ h, float* __restrict__ s) {
  __shared__ float ssc[NN];
  __shared__ float sred[8];
  __shared__ float sagg[4][DD];
  __shared__ float sxi[DD];
  __shared__ float ragg[DD];
  __shared__ float spool[4];

  const int t = threadIdx.x;
  const int w = t >> 6, l = t & 63;
  const int b = blockIdx.x >> 9;
  const int i = blockIdx.x & (NN - 1);
  const float* xb = x + (size_t)b * NN * DD;

  if (t < 64) sxi[t] = xb[(size_t)i * DD + t];

  const float* p0 = sTp + ((size_t)(0 * 4 + b)) * NN * NN;
  const float* p1 = sTp + ((size_t)(1 * 4 + b)) * NN * NN;
  float sc0 = p0[(size_t)t * NN + i] + p1[(size_t)t * NN + i];
  float sc1 = p0[(size_t)(t + 256) * NN + i] + p1[(size_t)(t + 256) * NN + i];

  float m = fmaxf(sc0, sc1);
  #pragma unroll
  for (int off = 32; off; off >>= 1) m = fmaxf(m, __shfl_xor(m, off, 64));
  if (l == 0) sred[w] = m;
  __syncthreads();
  m = fmaxf(fmaxf(sred[0], sred[1]), fmaxf(sred[2], sred[3]));

  const float L2E = 1.4426950408889634f;
  float e0 = __builtin_amdgcn_exp2f((sc0 - m) * L2E);
  float e1 = __builtin_amdgcn_exp2f((sc1 - m) * L2E);
  float ps = e0 + e1;
  #pragma unroll
  for (int off = 32; off; off >>= 1) ps += __shfl_xor(ps, off, 64);
  if (l == 0) sred[4 + w] = ps;
  __syncthreads();
  const float S = sred[4] + sred[5] + sred[6] + sred[7];
  const float inv = 1.f / S;
  ssc[t] = e0 * inv;
  ssc[t + 256] = e1 * inv;
  __syncthreads();

  const int c2 = t >> 6, d = t & 63;
  float part = 0.f;
  #pragma unroll 4
  for (int q = 0; q < 128; ++q) {
    const int j = c2 * 128 + q;
    part = fmaf(ssc[j], xb[(size_t)j * DD + d], part);
  }
  sagg[c2][d] = part;
  __syncthreads();
  if (t < 64) ragg[t] = sagg[0][t] + sagg[1][t] + sagg[2][t] + sagg[3][t];
  __syncthreads();

  const int e = w * 16 + (l & 15), dg = l >> 4;
  float acc = 0.f;
  #pragma unroll
  for (int q = 0; q < 16; ++q) {
    const int dd2 = dg * 16 + q;
    acc = fmaf(ragg[dd2], pwa[dd2 * 64 + e], acc);
    acc = fmaf(sxi[dd2], pwoa[dd2 * 64 + e], acc);
  }
  acc += __shfl_xor(acc, 16, 64);
  acc += __shfl_xor(acc, 32, 64);
  acc += pwab[e] + pwob[e];
  float hb = (acc - mu[e]) * rsqrtf(var[e] + 1e-5f) * gam[e] + bet[e];
  const float SC = 1.0507009873554805f, AL = 1.6732632423543772f;
  float hv = hb > 0.f ? SC * hb : SC * AL * expm1f(hb);
  if (dg == 0) h[((size_t)(b * NN + i)) * DD + e] = hv;

  float p = hv * poolw[e];
  p += __shfl_xor(p, 1, 64);
  p += __shfl_xor(p, 2, 64);
  p += __shfl_xor(p, 4, 64);
  p += __shfl_xor(p, 8, 64);
  if (l == 0) spool[w] = p;
  __syncthreads();
  if (t == 0) {
    float tot = spool[0] + spool[1] + spool[2] + spool[3] + poolb[0];
    s[b * NN + i] = 1.f / (1.f + expf(-tot));
  }
}

// ====== Kernel C: per-batch top-k via rank selection (exact tie semantics) ===
__global__ __launch_bounds__(512) void k_topk(
    const float* __restrict__ s, const float* __restrict__ h,
    float* __restrict__ out) {
  __shared__ float sv[NN];
  __shared__ int inv[NKEEP];
  const int b = blockIdx.x, t = threadIdx.x;
  sv[t] = s[b * NN + t];
  __syncthreads();

  const float my = sv[t];
  int r = 0;
  #pragma unroll 4
  for (int j0 = 0; j0 < NN; j0 += 4) {
    float4 v = *reinterpret_cast<const float4*>(&sv[j0]);
    r += (v.x > my) || (v.x == my && (j0 + 0) < t);
    r += (v.y > my) || (v.y == my && (j0 + 1) < t);
    r += (v.z > my) || (v.z == my && (j0 + 2) < t);
    r += (v.w > my) || (v.w == my && (j0 + 3) < t);
  }
  if (r < NKEEP) inv[r] = t;
  __syncthreads();

  for (int pos = t; pos < NKEEP * DD; pos += 512) {
    const int kk = pos >> 6, d = pos & 63;
    const int i = inv[kk];
    out[((size_t)b * NKEEP + kk) * DD + d] =
        h[((size_t)b * NN + i) * DD + d] * sv[i];
  }
}

extern "C" void kernel_launch(void* const* d_in, const int* in_sizes, int n_in,
                              void* d_out, int out_size, void* d_ws, size_t ws_size,
                              hipStream_t stream) {
  const float* x     = (const float*)d_in[0];
  const float* apw   = (const float*)d_in[1];
  const float* apb   = (const float*)d_in[2];
  const float* aw    = (const float*)d_in[3];
  const float* pwa   = (const float*)d_in[4];
  const float* pwab  = (const float*)d_in[5];
  const float* pwoa  = (const float*)d_in[6];
  const float* pwob  = (const float*)d_in[7];
  const float* gam   = (const float*)d_in[8];
  const float* bet   = (const float*)d_in[9];
  const float* mu    = (const float*)d_in[10];
  const float* var   = (const float*)d_in[11];
  const float* poolw = (const float*)d_in[12];
  const float* poolb = (const float*)d_in[13];
  float* out = (float*)d_out;

  float* sTp = (float*)d_ws;                          // 2*4*512*512 f = 8 MB
  float* h   = sTp + (size_t)2 * BSZ * NN * NN;       // 131072 f
  float* s   = h + (size_t)BSZ * NN * DD;             // 2048 f

  k_score<<<1024, 256, 0, stream>>>(x, apw, apb, aw, sTp);
  k_soft<<<BSZ * NN, 256, 0, stream>>>(x, sTp, pwa, pwab, pwoa, pwob,
                                       gam, bet, mu, var, poolw, poolb, h, s);
  k_topk<<<BSZ, 512, 0, stream>>>(s, h, out);
}

// Round 5
// 105.827 us; speedup vs baseline: 1.0461x; 1.0461x over previous
//
#include <hip/hip_runtime.h>
#include <hip/hip_bf16.h>
#include <math.h>

#define BSZ 4
#define NN 512
#define DD 64
#define NKEEP 256

typedef __attribute__((ext_vector_type(8))) short short8;
typedef __attribute__((ext_vector_type(4))) float f32x4;

__device__ __forceinline__ ushort f2bf_rne(float f) {
  union { float f; unsigned u; } v; v.f = f;
  unsigned r = v.u + 0x7fffu + ((v.u >> 16) & 1u);
  return (ushort)(r >> 16);
}
__device__ __forceinline__ float bf2f(ushort h) {
  union { unsigned u; float f; } v; v.u = ((unsigned)h) << 16;
  return v.f;
}
__device__ __forceinline__ float fast_tanh(float x) {
  float e = __builtin_amdgcn_exp2f(x * 2.8853900817779268f);
  float r = __builtin_amdgcn_rcpf(e + 1.0f);
  return 1.0f - 2.0f * r;
}
__device__ __forceinline__ float rdlane(float v, int lane) {
  return __uint_as_float(__builtin_amdgcn_readlane(__float_as_uint(v), lane));
}

// ============ Kernel A: symmetric scores, coalesced dual-store ==============
// grid = (b4, it32, jq4) = 512 blocks, 256 thr (4 waves).
// Block: i-tile [it*16,+16), j-range [jq*128,+128), all 64 e (8 rounds of 8).
// Owned pairs: jv >= iv.  Upper store sT[iv][jv] as float4 rows (64B sectors);
// mirror store sT[jv][iv] as 16-lane 64B row segments.  Single fp32 plane.
__global__ __launch_bounds__(256, 4) void k_score(
    const float* __restrict__ x, const float* __restrict__ apw,
    const float* __restrict__ apb, const float* __restrict__ aw,
    float* __restrict__ sT) {
  __shared__ ushort Y8h[8 * 16 * 64];  // 16 KB, swizzled
  __shared__ ushort Y8l[8 * 16 * 64];  // 16 KB

  const int t = threadIdx.x;
  const int w = t >> 6, l = t & 63;
  const int bid = blockIdx.x;
  const int jq = bid & 3;
  const int it = (bid >> 2) & 31;
  const int b = bid >> 7;
  const int i0 = it * 16;
  const int jb0 = jq * 128;
  if (jb0 + 128 <= i0) return;  // entirely below diagonal: mirror covers

  const float* xb = x + (size_t)b * NN * DD;
  const int j0 = jb0 + w * 32;
  const bool wave_active = (j0 + 32 > i0);

  // ---- Xi slice into registers for Y-build (all threads) ----
  const int p_e = t >> 5;            // e sub-index 0..7
  const int q = t & 31;
  const int ih = (q >> 4) * 8;       // i base (0 or 8)
  const int d0 = (q & 15) * 4;       // d quad base
  float xi_r[8][4];
  #pragma unroll
  for (int i2 = 0; i2 < 8; ++i2) {
    float4 v = *reinterpret_cast<const float4*>(xb + (size_t)(i0 + ih + i2) * DD + d0);
    xi_r[i2][0] = v.x; xi_r[i2][1] = v.y; xi_r[i2][2] = v.z; xi_r[i2][3] = v.w;
  }

  // ---- A fragments (Xj) split hi/lo, e-independent ----
  short8 ah[2][2], al[2][2];
  if (wave_active) {
    const int g = l >> 4;
    #pragma unroll
    for (int jt = 0; jt < 2; ++jt) {
      const int j = j0 + jt * 16 + (l & 15);
      #pragma unroll
      for (int ks = 0; ks < 2; ++ks) {
        const float* xr = xb + (size_t)j * DD + ks * 32 + g * 8;
        float4 u0 = *reinterpret_cast<const float4*>(xr);
        float4 u1 = *reinterpret_cast<const float4*>(xr + 4);
        float vv[8] = {u0.x, u0.y, u0.z, u0.w, u1.x, u1.y, u1.z, u1.w};
        short8 hh, ll;
        #pragma unroll
        for (int qq = 0; qq < 8; ++qq) {
          ushort hq = f2bf_rne(vv[qq]);
          hh[qq] = (short)hq;
          ll[qq] = (short)f2bf_rne(vv[qq] - bf2f(hq));
        }
        ah[jt][ks] = hh; al[jt][ks] = ll;
      }
    }
  }

  f32x4 srews[2];
  srews[0] = (f32x4){0.f, 0.f, 0.f, 0.f};
  srews[1] = (f32x4){0.f, 0.f, 0.f, 0.f};

  #pragma unroll 1
  for (int r = 0; r < 8; ++r) {
    // ---- Y8 build: e = r*8 + p_e; thread covers 8 i x 4 d (all threads) ----
    {
      const int e = r * 8 + p_e;
      float wt[4];
      #pragma unroll
      for (int k = 0; k < 4; ++k) wt[k] = apw[(d0 + k) * 64 + e];
      #pragma unroll
      for (int i2 = 0; i2 < 8; ++i2) {
        const int i = ih + i2;
        ushort h4[4], l4[4];
        #pragma unroll
        for (int k = 0; k < 4; ++k) {
          const float v = xi_r[i2][k] * wt[k];
          h4[k] = f2bf_rne(v);
          l4[k] = f2bf_rne(v - bf2f(h4[k]));
        }
        uint2 hw, lw;
        hw.x = (uint)h4[0] | ((uint)h4[1] << 16);
        hw.y = (uint)h4[2] | ((uint)h4[3] << 16);
        lw.x = (uint)l4[0] | ((uint)l4[1] << 16);
        lw.y = (uint)l4[2] | ((uint)l4[3] << 16);
        const int byteoff = (p_e * 2048 + (i * 64 + d0) * 2) ^ ((i & 7) << 4);
        *reinterpret_cast<uint2*>(reinterpret_cast<char*>(Y8h) + byteoff) = hw;
        *reinterpret_cast<uint2*>(reinterpret_cast<char*>(Y8l) + byteoff) = lw;
      }
    }
    __syncthreads();  // Y8 published

    if (wave_active) {
      const int il = l & 15, g = l >> 4;
      #pragma unroll
      for (int p = 0; p < 8; ++p) {
        const int e = r * 8 + p;
        short8 bh[2], bl[2];
        #pragma unroll
        for (int ks = 0; ks < 2; ++ks) {
          const int byteoff =
              (p * 2048 + (il * 64 + ks * 32 + g * 8) * 2) ^ ((il & 7) << 4);
          bh[ks] = *reinterpret_cast<const short8*>(
              reinterpret_cast<const char*>(Y8h) + byteoff);
          bl[ks] = *reinterpret_cast<const short8*>(
              reinterpret_cast<const char*>(Y8l) + byteoff);
        }
        f32x4 acc[2];
        acc[0] = (f32x4){0.f, 0.f, 0.f, 0.f};
        acc[1] = (f32x4){0.f, 0.f, 0.f, 0.f};
        #pragma unroll
        for (int jt = 0; jt < 2; ++jt)
          #pragma unroll
          for (int ks = 0; ks < 2; ++ks) {
            acc[jt] = __builtin_amdgcn_mfma_f32_16x16x32_bf16(ah[jt][ks], bh[ks], acc[jt], 0, 0, 0);
            acc[jt] = __builtin_amdgcn_mfma_f32_16x16x32_bf16(ah[jt][ks], bl[ks], acc[jt], 0, 0, 0);
            acc[jt] = __builtin_amdgcn_mfma_f32_16x16x32_bf16(al[jt][ks], bh[ks], acc[jt], 0, 0, 0);
          }
        const float bias = apb[e], awv = aw[e];
        #pragma unroll
        for (int jt = 0; jt < 2; ++jt)
          #pragma unroll
          for (int rr = 0; rr < 4; ++rr)
            srews[jt][rr] += awv * fast_tanh(acc[jt][rr] + bias);
      }
    }
    __syncthreads();  // Y8 consumed
  }

  // ---- stores ----
  if (wave_active) {
    const int il = l & 15, g = l >> 4;
    const int iv = i0 + il;
    float* plane = sT + (size_t)b * NN * NN;
    #pragma unroll
    for (int jt = 0; jt < 2; ++jt) {
      const int jvb = j0 + jt * 16 + g * 4;  // lane's float4 col base
      if (j0 + jt * 16 >= i0 + 16) {
        // fully above diagonal: vectorized upper + full mirror rows
        *reinterpret_cast<f32x4*>(plane + (size_t)iv * NN + jvb) = srews[jt];
        #pragma unroll
        for (int rr = 0; rr < 4; ++rr)
          plane[(size_t)(jvb + rr) * NN + iv] = srews[jt][rr];
      } else {
        // diagonal overlap: per-element masked
        #pragma unroll
        for (int rr = 0; rr < 4; ++rr) {
          const int jv = jvb + rr;
          const float v = srews[jt][rr];
          if (jv >= iv) plane[(size_t)iv * NN + jv] = v;
          if (jv > iv) plane[(size_t)jv * NN + iv] = v;
        }
      }
    }
  }
}

// ====== Kernel B: 8 rows/block; wave owns 2 rows: softmax+agg+h+BN+SELU+s ====
__global__ __launch_bounds__(256) void k_soft(
    const float* __restrict__ x, const float* __restrict__ sT,
    const float* __restrict__ pwa, const float* __restrict__ pwab,
    const float* __restrict__ pwoa, const float* __restrict__ pwob,
    const float* __restrict__ gam, const float* __restrict__ bet,
    const float* __restrict__ mu, const float* __restrict__ var,
    const float* __restrict__ poolw, const float* __restrict__ poolb,
    float* __restrict__ h, float* __restrict__ s) {
  __shared__ float shm[4][2][2][64];  // [wave][row][{agg,xi}][d]

  const int t = threadIdx.x;
  const int w = t >> 6, l = t & 63;
  const int b = blockIdx.x >> 6;
  const int ig = blockIdx.x & 63;
  const int i_r0 = ig * 8 + w * 2;
  const int i_r1 = i_r0 + 1;
  const float* xb = x + (size_t)b * NN * DD;
  const float* plane = sT + (size_t)b * NN * NN;

  // ---- P1: softmax of rows r0, r1 (att kept in registers) ----
  float a0[8], a1[8];
  #pragma unroll
  for (int k = 0; k < 8; ++k) {
    a0[k] = plane[(size_t)i_r0 * NN + k * 64 + l];
    a1[k] = plane[(size_t)i_r1 * NN + k * 64 + l];
  }
  float m0 = a0[0], m1 = a1[0];
  #pragma unroll
  for (int k = 1; k < 8; ++k) { m0 = fmaxf(m0, a0[k]); m1 = fmaxf(m1, a1[k]); }
  #pragma unroll
  for (int off = 32; off; off >>= 1) {
    m0 = fmaxf(m0, __shfl_xor(m0, off, 64));
    m1 = fmaxf(m1, __shfl_xor(m1, off, 64));
  }
  const float L2E = 1.4426950408889634f;
  float ps0 = 0.f, ps1 = 0.f;
  #pragma unroll
  for (int k = 0; k < 8; ++k) {
    a0[k] = __builtin_amdgcn_exp2f((a0[k] - m0) * L2E);
    a1[k] = __builtin_amdgcn_exp2f((a1[k] - m1) * L2E);
    ps0 += a0[k]; ps1 += a1[k];
  }
  #pragma unroll
  for (int off = 32; off; off >>= 1) {
    ps0 += __shfl_xor(ps0, off, 64);
    ps1 += __shfl_xor(ps1, off, 64);
  }
  const float inv0 = 1.f / ps0, inv1 = 1.f / ps1;
  #pragma unroll
  for (int k = 0; k < 8; ++k) { a0[k] *= inv0; a1[k] *= inv1; }

  // ---- P2: agg GEMV, lane owns d = l; att broadcast via readlane ----
  float g0 = 0.f, g1 = 0.f;
  #pragma unroll
  for (int k = 0; k < 8; ++k) {
    #pragma unroll 8
    for (int jj = 0; jj < 64; ++jj) {
      const float xv = xb[(size_t)(k * 64 + jj) * DD + l];
      g0 = fmaf(rdlane(a0[k], jj), xv, g0);
      g1 = fmaf(rdlane(a1[k], jj), xv, g1);
    }
  }

  // ---- P3: h = agg@pwa + xi@pwoa (+biases), BN, SELU, pool ----
  shm[w][0][0][l] = g0;
  shm[w][1][0][l] = g1;
  shm[w][0][1][l] = xb[(size_t)i_r0 * DD + l];
  shm[w][1][1][l] = xb[(size_t)i_r1 * DD + l];
  // same-wave LDS write->read: program order, no barrier needed
  float acc0 = 0.f, acc1 = 0.f;
  #pragma unroll 8
  for (int d = 0; d < 64; ++d) {
    const float wa = pwa[d * 64 + l], wo = pwoa[d * 64 + l];
    acc0 = fmaf(shm[w][0][0][d], wa, acc0);
    acc0 = fmaf(shm[w][0][1][d], wo, acc0);
    acc1 = fmaf(shm[w][1][0][d], wa, acc1);
    acc1 = fmaf(shm[w][1][1][d], wo, acc1);
  }
  const float bsum = pwab[l] + pwob[l];
  acc0 += bsum; acc1 += bsum;
  const float bnscale = rsqrtf(var[l] + 1e-5f) * gam[l];
  const float bnm = mu[l], bnb = bet[l];
  float hb0 = (acc0 - bnm) * bnscale + bnb;
  float hb1 = (acc1 - bnm) * bnscale + bnb;
  const float SC = 1.0507009873554805f, AL = 1.6732632423543772f;
  float hv0 = hb0 > 0.f ? SC * hb0 : SC * AL * expm1f(hb0);
  float hv1 = hb1 > 0.f ? SC * hb1 : SC * AL * expm1f(hb1);
  h[((size_t)(b * NN + i_r0)) * DD + l] = hv0;
  h[((size_t)(b * NN + i_r1)) * DD + l] = hv1;

  float p0 = hv0 * poolw[l], p1 = hv1 * poolw[l];
  #pragma unroll
  for (int off = 32; off; off >>= 1) {
    p0 += __shfl_xor(p0, off, 64);
    p1 += __shfl_xor(p1, off, 64);
  }
  if (l == 0) {
    s[b * NN + i_r0] = 1.f / (1.f + expf(-(p0 + poolb[0])));
    s[b * NN + i_r1] = 1.f / (1.f + expf(-(p1 + poolb[0])));
  }
}

// ====== Kernel C: per-batch top-k via rank selection (exact tie semantics) ===
__global__ __launch_bounds__(512) void k_topk(
    const float* __restrict__ s, const float* __restrict__ h,
    float* __restrict__ out) {
  __shared__ float sv[NN];
  __shared__ int inv[NKEEP];
  const int b = blockIdx.x, t = threadIdx.x;
  sv[t] = s[b * NN + t];
  __syncthreads();

  const float my = sv[t];
  int r = 0;
  #pragma unroll 4
  for (int j0 = 0; j0 < NN; j0 += 4) {
    float4 v = *reinterpret_cast<const float4*>(&sv[j0]);
    r += (v.x > my) || (v.x == my && (j0 + 0) < t);
    r += (v.y > my) || (v.y == my && (j0 + 1) < t);
    r += (v.z > my) || (v.z == my && (j0 + 2) < t);
    r += (v.w > my) || (v.w == my && (j0 + 3) < t);
  }
  if (r < NKEEP) inv[r] = t;
  __syncthreads();

  for (int pos = t; pos < NKEEP * DD; pos += 512) {
    const int kk = pos >> 6, d = pos & 63;
    const int i = inv[kk];
    out[((size_t)b * NKEEP + kk) * DD + d] =
        h[((size_t)b * NN + i) * DD + d] * sv[i];
  }
}

extern "C" void kernel_launch(void* const* d_in, const int* in_sizes, int n_in,
                              void* d_out, int out_size, void* d_ws, size_t ws_size,
                              hipStream_t stream) {
  const float* x     = (const float*)d_in[0];
  const float* apw   = (const float*)d_in[1];
  const float* apb   = (const float*)d_in[2];
  const float* aw    = (const float*)d_in[3];
  const float* pwa   = (const float*)d_in[4];
  const float* pwab  = (const float*)d_in[5];
  const float* pwoa  = (const float*)d_in[6];
  const float* pwob  = (const float*)d_in[7];
  const float* gam   = (const float*)d_in[8];
  const float* bet   = (const float*)d_in[9];
  const float* mu    = (const float*)d_in[10];
  const float* var   = (const float*)d_in[11];
  const float* poolw = (const float*)d_in[12];
  const float* poolb = (const float*)d_in[13];
  float* out = (float*)d_out;

  float* sT = (float*)d_ws;                     // 4*512*512 f = 4 MB
  float* h  = sT + (size_t)BSZ * NN * NN;       // 131072 f
  float* s  = h + (size_t)BSZ * NN * DD;        // 2048 f

  k_score<<<512, 256, 0, stream>>>(x, apw, apb, aw, sT);
  k_soft<<<BSZ * 64, 256, 0, stream>>>(x, sT, pwa, pwab, pwoa, pwob,
                                       gam, bet, mu, var, poolw, poolb, h, s);
  k_topk<<<BSZ, 512, 0, stream>>>(s, h, out);
}

// Round 6
// 82.300 us; speedup vs baseline: 1.3451x; 1.2859x over previous
//
#include <hip/hip_runtime.h>
#include <hip/hip_bf16.h>
#include <math.h>

#define BSZ 4
#define NN 512
#define DD 64
#define NKEEP 256

typedef __attribute__((ext_vector_type(8))) short short8;
typedef __attribute__((ext_vector_type(4))) float f32x4;

__device__ __forceinline__ ushort f2bf_rne(float f) {
  union { float f; unsigned u; } v; v.f = f;
  unsigned r = v.u + 0x7fffu + ((v.u >> 16) & 1u);
  return (ushort)(r >> 16);
}
__device__ __forceinline__ float bf2f(ushort h) {
  union { unsigned u; float f; } v; v.u = ((unsigned)h) << 16;
  return v.f;
}
__device__ __forceinline__ float fast_tanh(float x) {
  float e = __builtin_amdgcn_exp2f(x * 2.8853900817779268f);
  float r = __builtin_amdgcn_rcpf(e + 1.0f);
  return 1.0f - 2.0f * r;
}
__device__ __forceinline__ float rdlane(float v, int lane) {
  return __uint_as_float(__builtin_amdgcn_readlane(__float_as_uint(v), lane));
}

// ============ Kernel A: symmetric scores, dbuf-Y, LDS-transpose store ========
// grid = (b4, it32, jq4) = 512 blocks, 256 thr (4 waves x 32 j).
// Owned pairs: jv >= iv. Upper rows via LDS transpose (512B row segments);
// mirror via register-direct 4row x 64B (R3-proven). Diag blocks: masked.
__global__ __launch_bounds__(256, 2) void k_score(
    const float* __restrict__ x, const float* __restrict__ apw,
    const float* __restrict__ apb, const float* __restrict__ aw,
    float* __restrict__ sT) {
  __shared__ ushort Yh[2][8 * 16 * 64];  // 2 x 16 KB, swizzled
  __shared__ ushort Yl[2][8 * 16 * 64];  // 2 x 16 KB

  const int t = threadIdx.x;
  const int w = t >> 6, l = t & 63;
  const int bid = blockIdx.x;
  const int jq = bid & 3;
  const int it = (bid >> 2) & 31;
  const int b = bid >> 7;
  const int i0 = it * 16;
  const int jb0 = jq * 128;
  if (jb0 + 128 <= i0) return;           // below diagonal: mirror covers
  const bool fast = (jb0 >= i0 + 16);    // whole tile strictly above diag

  const float* xb = x + (size_t)b * NN * DD;
  const int j0 = jb0 + w * 32;
  const bool wave_active = (j0 + 32 > i0);

  // ---- Xi slice into registers for Y-build ----
  const int p_e = t >> 5;            // e sub-index 0..7
  const int q = t & 31;
  const int ih = (q >> 4) * 8;       // i base (0 or 8)
  const int d0 = (q & 15) * 4;       // d quad base
  float xi_r[8][4];
  #pragma unroll
  for (int i2 = 0; i2 < 8; ++i2) {
    float4 v = *reinterpret_cast<const float4*>(xb + (size_t)(i0 + ih + i2) * DD + d0);
    xi_r[i2][0] = v.x; xi_r[i2][1] = v.y; xi_r[i2][2] = v.z; xi_r[i2][3] = v.w;
  }

  // ---- A fragments (Xj) split hi/lo, e-independent ----
  short8 ah[2][2], al[2][2];
  if (wave_active) {
    const int g = l >> 4;
    #pragma unroll
    for (int jt = 0; jt < 2; ++jt) {
      const int j = j0 + jt * 16 + (l & 15);
      #pragma unroll
      for (int ks = 0; ks < 2; ++ks) {
        const float* xr = xb + (size_t)j * DD + ks * 32 + g * 8;
        float4 u0 = *reinterpret_cast<const float4*>(xr);
        float4 u1 = *reinterpret_cast<const float4*>(xr + 4);
        float vv[8] = {u0.x, u0.y, u0.z, u0.w, u1.x, u1.y, u1.z, u1.w};
        short8 hh, ll;
        #pragma unroll
        for (int qq = 0; qq < 8; ++qq) {
          ushort hq = f2bf_rne(vv[qq]);
          hh[qq] = (short)hq;
          ll[qq] = (short)f2bf_rne(vv[qq] - bf2f(hq));
        }
        ah[jt][ks] = hh; al[jt][ks] = ll;
      }
    }
  }

  // ---- Y build helper (all threads): e = rnd*8 + p_e into buffer bf ----
  auto build = [&](int rnd, int bf) {
    const int e = rnd * 8 + p_e;
    float wt[4];
    #pragma unroll
    for (int k = 0; k < 4; ++k) wt[k] = apw[(d0 + k) * 64 + e];
    #pragma unroll
    for (int i2 = 0; i2 < 8; ++i2) {
      const int i = ih + i2;
      ushort h4[4], l4[4];
      #pragma unroll
      for (int k = 0; k < 4; ++k) {
        const float v = xi_r[i2][k] * wt[k];
        h4[k] = f2bf_rne(v);
        l4[k] = f2bf_rne(v - bf2f(h4[k]));
      }
      uint2 hw, lw;
      hw.x = (uint)h4[0] | ((uint)h4[1] << 16);
      hw.y = (uint)h4[2] | ((uint)h4[3] << 16);
      lw.x = (uint)l4[0] | ((uint)l4[1] << 16);
      lw.y = (uint)l4[2] | ((uint)l4[3] << 16);
      const int byteoff = (p_e * 2048 + (i * 64 + d0) * 2) ^ ((i & 7) << 4);
      *reinterpret_cast<uint2*>(reinterpret_cast<char*>(Yh[bf]) + byteoff) = hw;
      *reinterpret_cast<uint2*>(reinterpret_cast<char*>(Yl[bf]) + byteoff) = lw;
    }
  };

  f32x4 srews[2];
  srews[0] = (f32x4){0.f, 0.f, 0.f, 0.f};
  srews[1] = (f32x4){0.f, 0.f, 0.f, 0.f};

  build(0, 0);

  #pragma unroll 1
  for (int r = 0; r < 8; ++r) {
    __syncthreads();                 // buf[r&1] ready; buf[(r+1)&1] free
    if (r < 7) build(r + 1, (r + 1) & 1);
    if (wave_active) {
      const char* Ph = reinterpret_cast<const char*>(Yh[r & 1]);
      const char* Pl = reinterpret_cast<const char*>(Yl[r & 1]);
      const int il = l & 15, g = l >> 4;
      #pragma unroll
      for (int p = 0; p < 8; ++p) {
        const int e = r * 8 + p;
        short8 bh[2], bl[2];
        #pragma unroll
        for (int ks = 0; ks < 2; ++ks) {
          const int byteoff =
              (p * 2048 + (il * 64 + ks * 32 + g * 8) * 2) ^ ((il & 7) << 4);
          bh[ks] = *reinterpret_cast<const short8*>(Ph + byteoff);
          bl[ks] = *reinterpret_cast<const short8*>(Pl + byteoff);
        }
        f32x4 acc[2];
        acc[0] = (f32x4){0.f, 0.f, 0.f, 0.f};
        acc[1] = (f32x4){0.f, 0.f, 0.f, 0.f};
        #pragma unroll
        for (int jt = 0; jt < 2; ++jt)
          #pragma unroll
          for (int ks = 0; ks < 2; ++ks) {
            acc[jt] = __builtin_amdgcn_mfma_f32_16x16x32_bf16(ah[jt][ks], bh[ks], acc[jt], 0, 0, 0);
            acc[jt] = __builtin_amdgcn_mfma_f32_16x16x32_bf16(ah[jt][ks], bl[ks], acc[jt], 0, 0, 0);
            acc[jt] = __builtin_amdgcn_mfma_f32_16x16x32_bf16(al[jt][ks], bh[ks], acc[jt], 0, 0, 0);
          }
        const float bias = apb[e], awv = aw[e];
        #pragma unroll
        for (int jt = 0; jt < 2; ++jt)
          #pragma unroll
          for (int rr = 0; rr < 4; ++rr)
            srews[jt][rr] += awv * fast_tanh(acc[jt][rr] + bias);
      }
    }
  }

  // ---- stores ----
  float* plane = sT + (size_t)b * NN * NN;
  const int il = l & 15, g = l >> 4;
  const int iv = i0 + il;
  if (fast) {
    // mirror: register-direct, 4 rows x 64B per instruction (clean pattern)
    #pragma unroll
    for (int jt = 0; jt < 2; ++jt)
      #pragma unroll
      for (int rr = 0; rr < 4; ++rr)
        plane[(size_t)(j0 + jt * 16 + g * 4 + rr) * NN + iv] = srews[jt][rr];
    // upper: transpose via swizzled LDS T[16][128] (alias dead Yh[0])
    float* T = reinterpret_cast<float*>(Yh[0]);
    #pragma unroll
    for (int jt = 0; jt < 2; ++jt)
      #pragma unroll
      for (int rr = 0; rr < 4; ++rr) {
        const int colw = w * 32 + jt * 16 + g * 4 + rr;
        const int byteoff = ((il * 128 + colw) * 4) ^ ((il & 7) << 4);
        *reinterpret_cast<float*>(reinterpret_cast<char*>(T) + byteoff) =
            srews[jt][rr];
      }
    __syncthreads();
    const int row = t >> 4, cb = (t & 15) * 8;
    const char* Tc = reinterpret_cast<const char*>(T);
    const int base = (row * 128 + cb) * 4;
    const int sw = (row & 7) << 4;
    f32x4 v0 = *reinterpret_cast<const f32x4*>(Tc + ((base) ^ sw));
    f32x4 v1 = *reinterpret_cast<const f32x4*>(Tc + ((base + 16) ^ sw));
    *reinterpret_cast<f32x4*>(plane + (size_t)(i0 + row) * NN + jb0 + cb) = v0;
    *reinterpret_cast<f32x4*>(plane + (size_t)(i0 + row) * NN + jb0 + cb + 4) = v1;
  } else if (wave_active) {
    // diagonal-straddling blocks: per-element masked, single-writer ownership
    #pragma unroll
    for (int jt = 0; jt < 2; ++jt)
      #pragma unroll
      for (int rr = 0; rr < 4; ++rr) {
        const int jv = j0 + jt * 16 + g * 4 + rr;
        const float v = srews[jt][rr];
        if (jv >= iv) plane[(size_t)iv * NN + jv] = v;
        if (jv > iv) plane[(size_t)jv * NN + iv] = v;
      }
  }
}

// ====== Kernel B: 8 rows/block; wave owns 2 rows: softmax+agg+h+BN+SELU+s ====
__global__ __launch_bounds__(256) void k_soft(
    const float* __restrict__ x, const float* __restrict__ sT,
    const float* __restrict__ pwa, const float* __restrict__ pwab,
    const float* __restrict__ pwoa, const float* __restrict__ pwob,
    const float* __restrict__ gam, const float* __restrict__ bet,
    const float* __restrict__ mu, const float* __restrict__ var,
    const float* __restrict__ poolw, const float* __restrict__ poolb,
    float* __restrict__ h, float* __restrict__ s) {
  __shared__ float shm[4][2][2][64];  // [wave][row][{agg,xi}][d]

  const int t = threadIdx.x;
  const int w = t >> 6, l = t & 63;
  const int b = blockIdx.x >> 6;
  const int ig = blockIdx.x & 63;
  const int i_r0 = ig * 8 + w * 2;
  const int i_r1 = i_r0 + 1;
  const float* xb = x + (size_t)b * NN * DD;
  const float* plane = sT + (size_t)b * NN * NN;

  float a0[8], a1[8];
  #pragma unroll
  for (int k = 0; k < 8; ++k) {
    a0[k] = plane[(size_t)i_r0 * NN + k * 64 + l];
    a1[k] = plane[(size_t)i_r1 * NN + k * 64 + l];
  }
  float m0 = a0[0], m1 = a1[0];
  #pragma unroll
  for (int k = 1; k < 8; ++k) { m0 = fmaxf(m0, a0[k]); m1 = fmaxf(m1, a1[k]); }
  #pragma unroll
  for (int off = 32; off; off >>= 1) {
    m0 = fmaxf(m0, __shfl_xor(m0, off, 64));
    m1 = fmaxf(m1, __shfl_xor(m1, off, 64));
  }
  const float L2E = 1.4426950408889634f;
  float ps0 = 0.f, ps1 = 0.f;
  #pragma unroll
  for (int k = 0; k < 8; ++k) {
    a0[k] = __builtin_amdgcn_exp2f((a0[k] - m0) * L2E);
    a1[k] = __builtin_amdgcn_exp2f((a1[k] - m1) * L2E);
    ps0 += a0[k]; ps1 += a1[k];
  }
  #pragma unroll
  for (int off = 32; off; off >>= 1) {
    ps0 += __shfl_xor(ps0, off, 64);
    ps1 += __shfl_xor(ps1, off, 64);
  }
  const float inv0 = 1.f / ps0, inv1 = 1.f / ps1;
  #pragma unroll
  for (int k = 0; k < 8; ++k) { a0[k] *= inv0; a1[k] *= inv1; }

  float g0 = 0.f, g1 = 0.f;
  #pragma unroll
  for (int k = 0; k < 8; ++k) {
    #pragma unroll 8
    for (int jj = 0; jj < 64; ++jj) {
      const float xv = xb[(size_t)(k * 64 + jj) * DD + l];
      g0 = fmaf(rdlane(a0[k], jj), xv, g0);
      g1 = fmaf(rdlane(a1[k], jj), xv, g1);
    }
  }

  shm[w][0][0][l] = g0;
  shm[w][1][0][l] = g1;
  shm[w][0][1][l] = xb[(size_t)i_r0 * DD + l];
  shm[w][1][1][l] = xb[(size_t)i_r1 * DD + l];
  float acc0 = 0.f, acc1 = 0.f;
  #pragma unroll 8
  for (int d = 0; d < 64; ++d) {
    const float wa = pwa[d * 64 + l], wo = pwoa[d * 64 + l];
    acc0 = fmaf(shm[w][0][0][d], wa, acc0);
    acc0 = fmaf(shm[w][0][1][d], wo, acc0);
    acc1 = fmaf(shm[w][1][0][d], wa, acc1);
    acc1 = fmaf(shm[w][1][1][d], wo, acc1);
  }
  const float bsum = pwab[l] + pwob[l];
  acc0 += bsum; acc1 += bsum;
  const float bnscale = rsqrtf(var[l] + 1e-5f) * gam[l];
  const float bnm = mu[l], bnb = bet[l];
  float hb0 = (acc0 - bnm) * bnscale + bnb;
  float hb1 = (acc1 - bnm) * bnscale + bnb;
  const float SC = 1.0507009873554805f, AL = 1.6732632423543772f;
  float hv0 = hb0 > 0.f ? SC * hb0 : SC * AL * expm1f(hb0);
  float hv1 = hb1 > 0.f ? SC * hb1 : SC * AL * expm1f(hb1);
  h[((size_t)(b * NN + i_r0)) * DD + l] = hv0;
  h[((size_t)(b * NN + i_r1)) * DD + l] = hv1;

  float p0 = hv0 * poolw[l], p1 = hv1 * poolw[l];
  #pragma unroll
  for (int off = 32; off; off >>= 1) {
    p0 += __shfl_xor(p0, off, 64);
    p1 += __shfl_xor(p1, off, 64);
  }
  if (l == 0) {
    s[b * NN + i_r0] = 1.f / (1.f + expf(-(p0 + poolb[0])));
    s[b * NN + i_r1] = 1.f / (1.f + expf(-(p1 + poolb[0])));
  }
}

// ====== Kernel C: per-batch top-k via rank selection (exact tie semantics) ===
__global__ __launch_bounds__(512) void k_topk(
    const float* __restrict__ s, const float* __restrict__ h,
    float* __restrict__ out) {
  __shared__ float sv[NN];
  __shared__ int inv[NKEEP];
  const int b = blockIdx.x, t = threadIdx.x;
  sv[t] = s[b * NN + t];
  __syncthreads();

  const float my = sv[t];
  int r = 0;
  #pragma unroll 4
  for (int j0 = 0; j0 < NN; j0 += 4) {
    float4 v = *reinterpret_cast<const float4*>(&sv[j0]);
    r += (v.x > my) || (v.x == my && (j0 + 0) < t);
    r += (v.y > my) || (v.y == my && (j0 + 1) < t);
    r += (v.z > my) || (v.z == my && (j0 + 2) < t);
    r += (v.w > my) || (v.w == my && (j0 + 3) < t);
  }
  if (r < NKEEP) inv[r] = t;
  __syncthreads();

  for (int pos = t; pos < NKEEP * DD; pos += 512) {
    const int kk = pos >> 6, d = pos & 63;
    const int i = inv[kk];
    out[((size_t)b * NKEEP + kk) * DD + d] =
        h[((size_t)b * NN + i) * DD + d] * sv[i];
  }
}

extern "C" void kernel_launch(void* const* d_in, const int* in_sizes, int n_in,
                              void* d_out, int out_size, void* d_ws, size_t ws_size,
                              hipStream_t stream) {
  const float* x     = (const float*)d_in[0];
  const float* apw   = (const float*)d_in[1];
  const float* apb   = (const float*)d_in[2];
  const float* aw    = (const float*)d_in[3];
  const float* pwa   = (const float*)d_in[4];
  const float* pwab  = (const float*)d_in[5];
  const float* pwoa  = (const float*)d_in[6];
  const float* pwob  = (const float*)d_in[7];
  const float* gam   = (const float*)d_in[8];
  const float* bet   = (const float*)d_in[9];
  const float* mu    = (const float*)d_in[10];
  const float* var   = (const float*)d_in[11];
  const float* poolw = (const float*)d_in[12];
  const float* poolb = (const float*)d_in[13];
  float* out = (float*)d_out;

  float* sT = (float*)d_ws;                     // 4*512*512 f = 4 MB
  float* h  = sT + (size_t)BSZ * NN * NN;       // 131072 f
  float* s  = h + (size_t)BSZ * NN * DD;        // 2048 f

  k_score<<<512, 256, 0, stream>>>(x, apw, apb, aw, sT);
  k_soft<<<BSZ * 64, 256, 0, stream>>>(x, sT, pwa, pwab, pwoa, pwob,
                                       gam, bet, mu, var, poolw, poolb, h, s);
  k_topk<<<BSZ, 512, 0, stream>>>(s, h, out);
}